// Round 16
// baseline (247.598 us; speedup 1.0000x reference)
//
#include <hip/hip_runtime.h>
#include <math.h>

#define D 64
#define S 4

// ---------------- workspace layout (float offsets) ----------------
#define WS_KEYS 0      // keys[S][D]
#define WS_ST   256    // st_norm[S]
#define WS_SUMS 260    // uw_sums[S] (atomic, zeroed each launch)
#define WS_LW   264    // last_writer[S] (int, -1 init)
#define WS_OUT1 272    // out1[D] (16B aligned)
#define WS_WCT  512    // wct[c][k][i] = Wq[(c*32+i)][k]  (2 chunks x 64 k x 32 dims)

__global__ void k_prep(const float* __restrict__ slots,
                       const float* __restrict__ ss,
                       const float* __restrict__ Wk,
                       const float* __restrict__ bk,
                       const float* __restrict__ Wq,
                       float* __restrict__ ws) {
  int d = threadIdx.x;  // 64 threads
  __shared__ float sl[S][D];
  for (int s = 0; s < S; ++s) sl[s][d] = slots[s * D + d];
  __syncthreads();
  float bkd = bk[d];
  for (int s = 0; s < S; ++s) {
    float acc = bkd;
    for (int k = 0; k < D; ++k) acc = fmaf(sl[s][k], Wk[d * D + k], acc);
    ws[WS_KEYS + s * D + d] = tanhf(acc);
  }
  // W chunk-transpose (32-dim chunks): wct[((c*64)+k)*32 + i] = Wq[(c*32+i)*64 + k]
  {
    int c = d >> 5, i = d & 31;
    for (int k = 0; k < D; ++k)
      ws[WS_WCT + ((c * 64 + k) * 32 + i)] = Wq[d * D + k];
  }
  if (d < S) {
    ws[WS_SUMS + d] = 0.f;
    ((int*)ws)[WS_LW + d] = -1;
  }
  if (d == 0) {
    float st[S]; float tot = 0.f;
    for (int s = 0; s < S; ++s) {
      float x = ss[s];
      float sp = log1pf(expf(-fabsf(x))) + fmaxf(x, 0.f);  // softplus
      st[s] = sp; tot += sp;
    }
    for (int s = 0; s < S; ++s) ws[WS_ST + s] = st[s] / tot;
  }
}

// NOTE: macro params must not collide with .x/.y/.z/.w member names
#define FMA4(A_, XS_, W_) \
  A_.x = fmaf(XS_, W_.x, A_.x); A_.y = fmaf(XS_, W_.y, A_.y); \
  A_.z = fmaf(XS_, W_.z, A_.z); A_.w = fmaf(XS_, W_.w, A_.w);

#define TANH1(V_) fmaf(-2.f, __builtin_amdgcn_rcpf(__expf(2.f * (V_)) + 1.f), 1.f)
#define TANH4(A_) { A_.x = TANH1(A_.x); A_.y = TANH1(A_.y); A_.z = TANH1(A_.z); A_.w = TANH1(A_.w); }

#define DOT4ACC(P_, A_, K_) \
  P_ = fmaf(A_.x, K_.x, P_); P_ = fmaf(A_.y, K_.y, P_); \
  P_ = fmaf(A_.z, K_.z, P_); P_ = fmaf(A_.w, K_.w, P_);

// one k-scalar for BOTH rows over 32 dims: 8 W float4s feed 16 FMA4s
#define QK2(XSA_, XSB_, KI_) { \
  float4 w0 = wb[(KI_) * 8 + 0], w1 = wb[(KI_) * 8 + 1]; \
  float4 w2 = wb[(KI_) * 8 + 2], w3 = wb[(KI_) * 8 + 3]; \
  float4 w4 = wb[(KI_) * 8 + 4], w5 = wb[(KI_) * 8 + 5]; \
  float4 w6 = wb[(KI_) * 8 + 6], w7 = wb[(KI_) * 8 + 7]; \
  FMA4(CA0, XSA_, w0) FMA4(CA1, XSA_, w1) FMA4(CA2, XSA_, w2) FMA4(CA3, XSA_, w3) \
  FMA4(CA4, XSA_, w4) FMA4(CA5, XSA_, w5) FMA4(CA6, XSA_, w6) FMA4(CA7, XSA_, w7) \
  FMA4(CB0, XSB_, w0) FMA4(CB1, XSB_, w1) FMA4(CB2, XSB_, w2) FMA4(CB3, XSB_, w3) \
  FMA4(CB4, XSB_, w4) FMA4(CB5, XSB_, w5) FMA4(CB6, XSB_, w6) FMA4(CB7, XSB_, w7) }

// one x-float4 (4 consecutive k) for both rows
#define QK8(XVA_, XVB_, KB_) \
  QK2(XVA_.x, XVB_.x, KB_)       QK2(XVA_.y, XVB_.y, (KB_) + 1) \
  QK2(XVA_.z, XVB_.z, (KB_) + 2) QK2(XVA_.w, XVB_.w, (KB_) + 3)

// 2 rows/lane, 2 chunks of 32 dims. unroll 8 deepens the independent FMA
// chains between x-load waits (R10's ILP profile) while keeping R15's
// halved x re-read traffic. Chains bitwise-identical to R15.
// B == gridDim.x * 512 exactly -> no guards.
__launch_bounds__(256)
__global__ void k_main(const float* __restrict__ item,
                       const float* __restrict__ wct,   // ws+WS_WCT
                       const float* __restrict__ keys,  // ws+WS_KEYS
                       const float* __restrict__ st4,   // ws+WS_ST
                       const float* __restrict__ bq,
                       float* red,                      // ws (atomics)
                       float* __restrict__ slot_weights,
                       float* __restrict__ selected,
                       int B) {
  __shared__ float red_sum[4][S];
  __shared__ int   red_lw[4][S];

  int t = threadIdx.x;
  long rA = (long)blockIdx.x * 512 + t;
  long rB = rA + 256;

  const float4* rowA = (const float4*)(item + rA * D);
  const float4* rowB = (const float4*)(item + rB * D);

  const float4* bq4 = (const float4*)bq;     // uniform
  const float4* kr  = (const float4*)keys;   // uniform

  float SA0 = 0.f, SA1 = 0.f, SA2 = 0.f, SA3 = 0.f;
  float SB0 = 0.f, SB1 = 0.f, SB2 = 0.f, SB3 = 0.f;

  #pragma unroll 1
  for (int c = 0; c < 2; ++c) {
    const float4* wb = (const float4*)wct + c * 512;   // 8KB slab, uniform
    float4 CA0 = bq4[c * 8 + 0], CA1 = bq4[c * 8 + 1];
    float4 CA2 = bq4[c * 8 + 2], CA3 = bq4[c * 8 + 3];
    float4 CA4 = bq4[c * 8 + 4], CA5 = bq4[c * 8 + 5];
    float4 CA6 = bq4[c * 8 + 6], CA7 = bq4[c * 8 + 7];
    float4 CB0 = CA0, CB1 = CA1, CB2 = CA2, CB3 = CA3;
    float4 CB4 = CA4, CB5 = CA5, CB6 = CA6, CB7 = CA7;

    #pragma unroll 8
    for (int kq = 0; kq < 16; ++kq) {
      float4 xa = rowA[kq];
      float4 xb = rowB[kq];
      QK8(xa, xb, kq * 4)
    }

    TANH4(CA0) TANH4(CA1) TANH4(CA2) TANH4(CA3)
    TANH4(CA4) TANH4(CA5) TANH4(CA6) TANH4(CA7)
    TANH4(CB0) TANH4(CB1) TANH4(CB2) TANH4(CB3)
    TANH4(CB4) TANH4(CB5) TANH4(CB6) TANH4(CB7)

    // sims over this chunk's 32 dims (ascending-dim order preserved)
    {
      const float4* k0 = kr + 0 * 16 + c * 8;
      DOT4ACC(SA0, CA0, k0[0]) DOT4ACC(SA0, CA1, k0[1]) DOT4ACC(SA0, CA2, k0[2]) DOT4ACC(SA0, CA3, k0[3])
      DOT4ACC(SA0, CA4, k0[4]) DOT4ACC(SA0, CA5, k0[5]) DOT4ACC(SA0, CA6, k0[6]) DOT4ACC(SA0, CA7, k0[7])
      DOT4ACC(SB0, CB0, k0[0]) DOT4ACC(SB0, CB1, k0[1]) DOT4ACC(SB0, CB2, k0[2]) DOT4ACC(SB0, CB3, k0[3])
      DOT4ACC(SB0, CB4, k0[4]) DOT4ACC(SB0, CB5, k0[5]) DOT4ACC(SB0, CB6, k0[6]) DOT4ACC(SB0, CB7, k0[7])
      const float4* k1 = kr + 1 * 16 + c * 8;
      DOT4ACC(SA1, CA0, k1[0]) DOT4ACC(SA1, CA1, k1[1]) DOT4ACC(SA1, CA2, k1[2]) DOT4ACC(SA1, CA3, k1[3])
      DOT4ACC(SA1, CA4, k1[4]) DOT4ACC(SA1, CA5, k1[5]) DOT4ACC(SA1, CA6, k1[6]) DOT4ACC(SA1, CA7, k1[7])
      DOT4ACC(SB1, CB0, k1[0]) DOT4ACC(SB1, CB1, k1[1]) DOT4ACC(SB1, CB2, k1[2]) DOT4ACC(SB1, CB3, k1[3])
      DOT4ACC(SB1, CB4, k1[4]) DOT4ACC(SB1, CB5, k1[5]) DOT4ACC(SB1, CB6, k1[6]) DOT4ACC(SB1, CB7, k1[7])
      const float4* k2 = kr + 2 * 16 + c * 8;
      DOT4ACC(SA2, CA0, k2[0]) DOT4ACC(SA2, CA1, k2[1]) DOT4ACC(SA2, CA2, k2[2]) DOT4ACC(SA2, CA3, k2[3])
      DOT4ACC(SA2, CA4, k2[4]) DOT4ACC(SA2, CA5, k2[5]) DOT4ACC(SA2, CA6, k2[6]) DOT4ACC(SA2, CA7, k2[7])
      DOT4ACC(SB2, CB0, k2[0]) DOT4ACC(SB2, CB1, k2[1]) DOT4ACC(SB2, CB2, k2[2]) DOT4ACC(SB2, CB3, k2[3])
      DOT4ACC(SB2, CB4, k2[4]) DOT4ACC(SB2, CB5, k2[5]) DOT4ACC(SB2, CB6, k2[6]) DOT4ACC(SB2, CB7, k2[7])
      const float4* k3 = kr + 3 * 16 + c * 8;
      DOT4ACC(SA3, CA0, k3[0]) DOT4ACC(SA3, CA1, k3[1]) DOT4ACC(SA3, CA2, k3[2]) DOT4ACC(SA3, CA3, k3[3])
      DOT4ACC(SA3, CA4, k3[4]) DOT4ACC(SA3, CA5, k3[5]) DOT4ACC(SA3, CA6, k3[6]) DOT4ACC(SA3, CA7, k3[7])
      DOT4ACC(SB3, CB0, k3[0]) DOT4ACC(SB3, CB1, k3[1]) DOT4ACC(SB3, CB2, k3[2]) DOT4ACC(SB3, CB3, k3[3])
      DOT4ACC(SB3, CB4, k3[4]) DOT4ACC(SB3, CB5, k3[5]) DOT4ACC(SB3, CB6, k3[6]) DOT4ACC(SB3, CB7, k3[7])
    }
  }

  float s0 = st4[0], s1 = st4[1], s2 = st4[2], s3 = st4[3];

  float uA[S], uB[S];
  int selA = 0, selB = 0;
  {
    float m = fmaxf(fmaxf(SA0, SA1), fmaxf(SA2, SA3));
    float e0 = expf(SA0 - m), e1 = expf(SA1 - m);
    float e2 = expf(SA2 - m), e3 = expf(SA3 - m);
    float se = e0 + e1 + e2 + e3;
    float w0 = e0 / se, w1 = e1 / se, w2 = e2 / se, w3 = e3 / se;
    *(float4*)(slot_weights + rA * S) = make_float4(w0, w1, w2, w3);
    uA[0] = w0 * s0; uA[1] = w1 * s1; uA[2] = w2 * s2; uA[3] = w3 * s3;
    float us = uA[0] + uA[1] + uA[2] + uA[3];
    uA[0] /= us; uA[1] /= us; uA[2] /= us; uA[3] /= us;
    float best = uA[0];
    if (uA[1] > best) { best = uA[1]; selA = 1; }
    if (uA[2] > best) { best = uA[2]; selA = 2; }
    if (uA[3] > best) { best = uA[3]; selA = 3; }
    selected[rA] = (float)selA;
  }
  {
    float m = fmaxf(fmaxf(SB0, SB1), fmaxf(SB2, SB3));
    float e0 = expf(SB0 - m), e1 = expf(SB1 - m);
    float e2 = expf(SB2 - m), e3 = expf(SB3 - m);
    float se = e0 + e1 + e2 + e3;
    float w0 = e0 / se, w1 = e1 / se, w2 = e2 / se, w3 = e3 / se;
    *(float4*)(slot_weights + rB * S) = make_float4(w0, w1, w2, w3);
    uB[0] = w0 * s0; uB[1] = w1 * s1; uB[2] = w2 * s2; uB[3] = w3 * s3;
    float us = uB[0] + uB[1] + uB[2] + uB[3];
    uB[0] /= us; uB[1] /= us; uB[2] /= us; uB[3] /= us;
    float best = uB[0];
    if (uB[1] > best) { best = uB[1]; selB = 1; }
    if (uB[2] > best) { best = uB[2]; selB = 2; }
    if (uB[3] > best) { best = uB[3]; selB = 3; }
    selected[rB] = (float)selB;
  }

  // ---- block reduction: uw sums (add) and last-writer (max) ----
  float r[S]; int l[S];
  #pragma unroll
  for (int s = 0; s < S; ++s) {
    r[s] = uA[s] + uB[s];
    l[s] = (selB == s) ? (int)rB : ((selA == s) ? (int)rA : -1);  // rB > rA
  }
  #pragma unroll
  for (int off = 32; off > 0; off >>= 1) {
    #pragma unroll
    for (int s = 0; s < S; ++s) {
      r[s] += __shfl_down(r[s], off);
      int m = __shfl_down(l[s], off);
      l[s] = l[s] > m ? l[s] : m;
    }
  }
  int lane = t & 63, wid = t >> 6;
  if (lane == 0) {
    #pragma unroll
    for (int s = 0; s < S; ++s) { red_sum[wid][s] = r[s]; red_lw[wid][s] = l[s]; }
  }
  __syncthreads();
  if (t < S) {
    float tot = red_sum[0][t] + red_sum[1][t] + red_sum[2][t] + red_sum[3][t];
    atomicAdd(&red[WS_SUMS + t], tot);
    int lm = red_lw[0][t];
    if (red_lw[1][t] > lm) lm = red_lw[1][t];
    if (red_lw[2][t] > lm) lm = red_lw[2][t];
    if (red_lw[3][t] > lm) lm = red_lw[3][t];
    atomicMax((int*)red + WS_LW + t, lm);
  }
}

__global__ void k_final(const float* __restrict__ item,
                        const float* __restrict__ slots,
                        const float* __restrict__ usage,
                        const float* __restrict__ Wv,
                        const float* __restrict__ bv,
                        float* ws,
                        float* __restrict__ out_ns,
                        float* __restrict__ out_nu,
                        int B) {
  int d = threadIdx.x;  // 64 threads
  __shared__ float mean[D];
  const int* lw = (const int*)ws + WS_LW;
  float nsv[S];
  for (int s = 0; s < S; ++s) {
    int w = lw[s];
    float v = (w >= 0) ? item[(size_t)w * D + d] : slots[s * D + d];
    nsv[s] = v;
    out_ns[s * D + d] = v;
  }
  mean[d] = (nsv[0] + nsv[1] + nsv[2] + nsv[3]) * 0.25f;
  __syncthreads();
  float acc = bv[d];
  for (int k = 0; k < D; ++k) acc = fmaf(mean[k], Wv[d * D + k], acc);
  ws[WS_OUT1 + d] = tanhf(acc);
  if (d < S) out_nu[d] = usage[d] * 0.9f + ws[WS_SUMS + d] / (float)B;
}

__global__ void k_bcast(const float* __restrict__ ws,
                        float4* __restrict__ out, long n4) {
  __shared__ float4 o4[16];
  if (threadIdx.x < 16) o4[threadIdx.x] = ((const float4*)(ws + WS_OUT1))[threadIdx.x];
  __syncthreads();
  long i = (long)blockIdx.x * blockDim.x + threadIdx.x;
  long stride = (long)gridDim.x * blockDim.x;
  for (; i < n4; i += stride) out[i] = o4[i & 15];
}

extern "C" void kernel_launch(void* const* d_in, const int* in_sizes, int n_in,
                              void* d_out, int out_size, void* d_ws, size_t ws_size,
                              hipStream_t stream) {
  const float* item  = (const float*)d_in[0];
  const float* slots = (const float*)d_in[1];
  const float* ss    = (const float*)d_in[2];
  const float* usage = (const float*)d_in[3];
  const float* Wq    = (const float*)d_in[4];
  const float* bq    = (const float*)d_in[5];
  const float* Wk    = (const float*)d_in[6];
  const float* bk    = (const float*)d_in[7];
  const float* Wv    = (const float*)d_in[8];
  const float* bv    = (const float*)d_in[9];
  int B = in_sizes[0] / D;
  float* ws = (float*)d_ws;

  float* out_output       = (float*)d_out;
  float* out_new_slots    = out_output + (size_t)B * D;
  float* out_new_usage    = out_new_slots + S * D;
  float* out_selected     = out_new_usage + S;
  float* out_slot_weights = out_selected + B;

  k_prep<<<1, 64, 0, stream>>>(slots, ss, Wk, bk, Wq, ws);
  k_main<<<B / 512, 256, 0, stream>>>(
      item, ws + WS_WCT, ws + WS_KEYS, ws + WS_ST, bq, ws,
      out_slot_weights, out_selected, B);
  k_final<<<1, 64, 0, stream>>>(item, slots, usage, Wv, bv, ws,
                                out_new_slots, out_new_usage, B);
  long n4 = (long)B * D / 4;
  k_bcast<<<2048, 256, 0, stream>>>(ws, (float4*)out_output, n4);
}

// Round 17
// 112.056 us; speedup vs baseline: 2.2096x; 2.2096x over previous
//
#include <hip/hip_runtime.h>
#include <math.h>

#define D 64
#define S 4

typedef short short8 __attribute__((ext_vector_type(8)));
typedef float f32x4 __attribute__((ext_vector_type(4)));

// ---------------- workspace layout (float offsets) ----------------
#define WS_KEYS 0      // keys[S][D]
#define WS_ST   256    // st_norm[S]
#define WS_SUMS 260    // uw_sums[S] (atomic, zeroed each launch)
#define WS_LW   264    // last_writer[S] (int, -1 init)
#define WS_OUT1 272    // out1[D] (16B aligned)
#define WS_WF   512    // W bf16 fragments: 3 levels x 8 planes x 512 ushort = 12288 ushort

__device__ __forceinline__ unsigned short f2bf(float f) {
  unsigned u = __float_as_uint(f);
  u += 0x7FFFu + ((u >> 16) & 1u);          // round-nearest-even to bf16
  return (unsigned short)(u >> 16);
}
__device__ __forceinline__ float bf2f(unsigned short h) {
  return __uint_as_float(((unsigned)h) << 16);
}

#define TANH1(V_) fmaf(-2.f, __builtin_amdgcn_rcpf(__expf(2.f * (V_)) + 1.f), 1.f)

__global__ void k_prep(const float* __restrict__ slots,
                       const float* __restrict__ ss,
                       const float* __restrict__ Wk,
                       const float* __restrict__ bk,
                       const float* __restrict__ Wq,
                       float* __restrict__ ws) {
  int d = threadIdx.x;  // 64 threads; d plays "lane" for fragment prep
  __shared__ float sl[S][D];
  for (int s = 0; s < S; ++s) sl[s][d] = slots[s * D + d];
  __syncthreads();
  float bkd = bk[d];
  for (int s = 0; s < S; ++s) {
    float acc = bkd;
    for (int k = 0; k < D; ++k) acc = fmaf(sl[s][k], Wk[d * D + k], acc);
    ws[WS_KEYS + s * D + d] = tanhf(acc);
  }
  // --- W split-bf16 fragments for mfma_f32_16x16x32_bf16 B-operand ---
  // plane p = h*4+nb ; element = lane*8 + j ; n = nb*16+(lane&15) ;
  // k = h*32 + (lane>>4)*8 + j  (same (lane>>4,j)->k map as the A side)
  {
    unsigned short* wf = (unsigned short*)(ws + WS_WF);
    int n15 = d & 15, kg = (d >> 4) * 8;
    for (int h = 0; h < 2; ++h)
      for (int nb = 0; nb < 4; ++nb) {
        int n = nb * 16 + n15;
        int kbase = h * 32 + kg;
        for (int j = 0; j < 8; ++j) {
          float v = Wq[n * D + kbase + j];
          unsigned short s1 = f2bf(v); float r1 = v - bf2f(s1);
          unsigned short s2 = f2bf(r1); float r2 = r1 - bf2f(s2);
          unsigned short s3 = f2bf(r2);
          int off = (h * 4 + nb) * 512 + d * 8 + j;
          wf[off] = s1; wf[4096 + off] = s2; wf[8192 + off] = s3;
        }
      }
  }
  if (d < S) {
    ws[WS_SUMS + d] = 0.f;
    ((int*)ws)[WS_LW + d] = -1;
  }
  if (d == 0) {
    float st[S]; float tot = 0.f;
    for (int s = 0; s < S; ++s) {
      float x = ss[s];
      float sp = log1pf(expf(-fabsf(x))) + fmaxf(x, 0.f);  // softplus
      st[s] = sp; tot += sp;
    }
    for (int s = 0; s < S; ++s) ws[WS_ST + s] = st[s] / tot;
  }
}

#define SPLITJ(H_, J_, V_) { \
  float v_ = (V_); \
  unsigned short s1_ = f2bf(v_); float r1_ = v_ - bf2f(s1_); \
  unsigned short s2_ = f2bf(r1_); float r2_ = r1_ - bf2f(s2_); \
  unsigned short s3_ = f2bf(r2_); \
  a1[H_][J_] = (short)s1_; a2[H_][J_] = (short)s2_; a3[H_][J_] = (short)s3_; }

// MFMA family kernel: W entirely register-resident as lane-distributed bf16
// fragments (3 split levels). Per wave-iter: 16 rows, 48 MFMAs (6 split terms
// x 2 K-halves x 4 n-blocks), epilogue sims via 16-lane shfl_xor tree.
// C/D layout (HW-verified m89): col=lane&15, row=(lane>>4)*4+reg.
// A/B use the same (lane>>4,j)->k map, so K-permutation cancels.
__launch_bounds__(256)
__global__ void k_main(const float* __restrict__ item,
                       const float* __restrict__ ws,    // keys/st + wf
                       const float* __restrict__ bq,
                       float* red,                      // ws (atomics)
                       float* __restrict__ slot_weights,
                       float* __restrict__ selected,
                       int B) {
  __shared__ float red_sum[4][S];
  __shared__ int   red_lw[4][S];

  int t = threadIdx.x;
  int w = t >> 6, lane = t & 63;
  int lrow = lane & 15, g = lane >> 4;
  long base = (long)blockIdx.x * 512;

  // ---- persistent W fragments: 24 short8 = 96 VGPR ----
  const short8* wfv = (const short8*)(ws + WS_WF);
  short8 B1[2][4], B2[2][4], B3[2][4];
  #pragma unroll
  for (int h = 0; h < 2; ++h)
    #pragma unroll
    for (int nb = 0; nb < 4; ++nb) {
      B1[h][nb] = wfv[(h * 4 + nb) * 64 + lane];
      B2[h][nb] = wfv[512 + (h * 4 + nb) * 64 + lane];
      B3[h][nb] = wfv[1024 + (h * 4 + nb) * 64 + lane];
    }

  // per-lane keys fragment and bias
  float kf[4][4], bqv[4];
  #pragma unroll
  for (int nb = 0; nb < 4; ++nb) {
    bqv[nb] = bq[nb * 16 + lrow];
    #pragma unroll
    for (int s = 0; s < S; ++s) kf[s][nb] = ws[WS_KEYS + s * D + nb * 16 + lrow];
  }
  float s0 = ws[WS_ST + 0], s1 = ws[WS_ST + 1];
  float s2 = ws[WS_ST + 2], s3 = ws[WS_ST + 3];

  float usum[S] = {0.f, 0.f, 0.f, 0.f};
  int   lmax[S] = {-1, -1, -1, -1};

  #pragma unroll 1
  for (int it = 0; it < 8; ++it) {
    long r0 = base + it * 64 + (long)w * 16;
    const float4* xr = (const float4*)(item + (r0 + lrow) * D);
    float4 p0 = xr[g * 2 + 0], p1 = xr[g * 2 + 1];
    float4 p2 = xr[8 + g * 2 + 0], p3 = xr[8 + g * 2 + 1];

    short8 a1[2], a2[2], a3[2];
    SPLITJ(0, 0, p0.x) SPLITJ(0, 1, p0.y) SPLITJ(0, 2, p0.z) SPLITJ(0, 3, p0.w)
    SPLITJ(0, 4, p1.x) SPLITJ(0, 5, p1.y) SPLITJ(0, 6, p1.z) SPLITJ(0, 7, p1.w)
    SPLITJ(1, 0, p2.x) SPLITJ(1, 1, p2.y) SPLITJ(1, 2, p2.z) SPLITJ(1, 3, p2.w)
    SPLITJ(1, 4, p3.x) SPLITJ(1, 5, p3.y) SPLITJ(1, 6, p3.z) SPLITJ(1, 7, p3.w)

    f32x4 acc[4];
    #pragma unroll
    for (int nb = 0; nb < 4; ++nb) acc[nb] = (f32x4){0.f, 0.f, 0.f, 0.f};

    #pragma unroll
    for (int h = 0; h < 2; ++h) {
      #pragma unroll
      for (int nb = 0; nb < 4; ++nb) {
        acc[nb] = __builtin_amdgcn_mfma_f32_16x16x32_bf16(a1[h], B1[h][nb], acc[nb], 0, 0, 0);
        acc[nb] = __builtin_amdgcn_mfma_f32_16x16x32_bf16(a1[h], B2[h][nb], acc[nb], 0, 0, 0);
        acc[nb] = __builtin_amdgcn_mfma_f32_16x16x32_bf16(a2[h], B1[h][nb], acc[nb], 0, 0, 0);
        acc[nb] = __builtin_amdgcn_mfma_f32_16x16x32_bf16(a1[h], B3[h][nb], acc[nb], 0, 0, 0);
        acc[nb] = __builtin_amdgcn_mfma_f32_16x16x32_bf16(a3[h], B1[h][nb], acc[nb], 0, 0, 0);
        acc[nb] = __builtin_amdgcn_mfma_f32_16x16x32_bf16(a2[h], B2[h][nb], acc[nb], 0, 0, 0);
      }
    }

    // epilogue: tanh + partial sims over this lane's 4 rows x 4 slots
    float ps[4][4];
    #pragma unroll
    for (int r_ = 0; r_ < 4; ++r_)
      #pragma unroll
      for (int s = 0; s < S; ++s) ps[r_][s] = 0.f;
    #pragma unroll
    for (int nb = 0; nb < 4; ++nb)
      #pragma unroll
      for (int r_ = 0; r_ < 4; ++r_) {
        float q = TANH1(acc[nb][r_] + bqv[nb]);
        #pragma unroll
        for (int s = 0; s < S; ++s) ps[r_][s] = fmaf(q, kf[s][nb], ps[r_][s]);
      }
    #pragma unroll
    for (int m_ = 1; m_ <= 8; m_ <<= 1)
      #pragma unroll
      for (int r_ = 0; r_ < 4; ++r_)
        #pragma unroll
        for (int s = 0; s < S; ++s) ps[r_][s] += __shfl_xor(ps[r_][s], m_);

    // owner lanes (lrow<4) finish row m = g*4 + lrow
    bool act = lrow < 4;
    float q0 = ps[0][0], q1 = ps[0][1], q2 = ps[0][2], q3 = ps[0][3];
    if (lrow == 1)      { q0 = ps[1][0]; q1 = ps[1][1]; q2 = ps[1][2]; q3 = ps[1][3]; }
    else if (lrow == 2) { q0 = ps[2][0]; q1 = ps[2][1]; q2 = ps[2][2]; q3 = ps[2][3]; }
    else if (lrow == 3) { q0 = ps[3][0]; q1 = ps[3][1]; q2 = ps[3][2]; q3 = ps[3][3]; }
    long grow = r0 + g * 4 + lrow;

    if (act) {
      float m = fmaxf(fmaxf(q0, q1), fmaxf(q2, q3));
      float e0 = expf(q0 - m), e1 = expf(q1 - m), e2 = expf(q2 - m), e3 = expf(q3 - m);
      float se = e0 + e1 + e2 + e3;
      float w0 = e0 / se, w1 = e1 / se, w2 = e2 / se, w3 = e3 / se;
      *(float4*)(slot_weights + grow * S) = make_float4(w0, w1, w2, w3);
      float u0 = w0 * s0, u1 = w1 * s1, u2 = w2 * s2, u3 = w3 * s3;
      float us = u0 + u1 + u2 + u3;
      u0 /= us; u1 /= us; u2 /= us; u3 /= us;
      int sel = 0; float best = u0;
      if (u1 > best) { best = u1; sel = 1; }
      if (u2 > best) { best = u2; sel = 2; }
      if (u3 > best) { best = u3; sel = 3; }
      selected[grow] = (float)sel;
      usum[0] += u0; usum[1] += u1; usum[2] += u2; usum[3] += u3;
      #pragma unroll
      for (int s = 0; s < S; ++s)
        if (sel == s && (int)grow > lmax[s]) lmax[s] = (int)grow;
    }
  }

  // ---- block reduction: uw sums (add) and last-writer (max) ----
  #pragma unroll
  for (int off = 32; off > 0; off >>= 1) {
    #pragma unroll
    for (int s = 0; s < S; ++s) {
      usum[s] += __shfl_down(usum[s], off);
      int m = __shfl_down(lmax[s], off);
      lmax[s] = lmax[s] > m ? lmax[s] : m;
    }
  }
  if (lane == 0) {
    #pragma unroll
    for (int s = 0; s < S; ++s) { red_sum[w][s] = usum[s]; red_lw[w][s] = lmax[s]; }
  }
  __syncthreads();
  if (t < S) {
    float tot = red_sum[0][t] + red_sum[1][t] + red_sum[2][t] + red_sum[3][t];
    atomicAdd(&red[WS_SUMS + t], tot);
    int lm = red_lw[0][t];
    if (red_lw[1][t] > lm) lm = red_lw[1][t];
    if (red_lw[2][t] > lm) lm = red_lw[2][t];
    if (red_lw[3][t] > lm) lm = red_lw[3][t];
    atomicMax((int*)red + WS_LW + t, lm);
  }
}

__global__ void k_final(const float* __restrict__ item,
                        const float* __restrict__ slots,
                        const float* __restrict__ usage,
                        const float* __restrict__ Wv,
                        const float* __restrict__ bv,
                        float* ws,
                        float* __restrict__ out_ns,
                        float* __restrict__ out_nu,
                        int B) {
  int d = threadIdx.x;  // 64 threads
  __shared__ float mean[D];
  const int* lw = (const int*)ws + WS_LW;
  float nsv[S];
  for (int s = 0; s < S; ++s) {
    int w = lw[s];
    float v = (w >= 0) ? item[(size_t)w * D + d] : slots[s * D + d];
    nsv[s] = v;
    out_ns[s * D + d] = v;
  }
  mean[d] = (nsv[0] + nsv[1] + nsv[2] + nsv[3]) * 0.25f;
  __syncthreads();
  float acc = bv[d];
  for (int k = 0; k < D; ++k) acc = fmaf(mean[k], Wv[d * D + k], acc);
  ws[WS_OUT1 + d] = tanhf(acc);
  if (d < S) out_nu[d] = usage[d] * 0.9f + ws[WS_SUMS + d] / (float)B;
}

__global__ void k_bcast(const float* __restrict__ ws,
                        float4* __restrict__ out, long n4) {
  __shared__ float4 o4[16];
  if (threadIdx.x < 16) o4[threadIdx.x] = ((const float4*)(ws + WS_OUT1))[threadIdx.x];
  __syncthreads();
  long i = (long)blockIdx.x * blockDim.x + threadIdx.x;
  long stride = (long)gridDim.x * blockDim.x;
  for (; i < n4; i += stride) out[i] = o4[i & 15];
}

extern "C" void kernel_launch(void* const* d_in, const int* in_sizes, int n_in,
                              void* d_out, int out_size, void* d_ws, size_t ws_size,
                              hipStream_t stream) {
  const float* item  = (const float*)d_in[0];
  const float* slots = (const float*)d_in[1];
  const float* ss    = (const float*)d_in[2];
  const float* usage = (const float*)d_in[3];
  const float* Wq    = (const float*)d_in[4];
  const float* bq    = (const float*)d_in[5];
  const float* Wk    = (const float*)d_in[6];
  const float* bk    = (const float*)d_in[7];
  const float* Wv    = (const float*)d_in[8];
  const float* bv    = (const float*)d_in[9];
  int B = in_sizes[0] / D;
  float* ws = (float*)d_ws;

  float* out_output       = (float*)d_out;
  float* out_new_slots    = out_output + (size_t)B * D;
  float* out_new_usage    = out_new_slots + S * D;
  float* out_selected     = out_new_usage + S;
  float* out_slot_weights = out_selected + B;

  k_prep<<<1, 64, 0, stream>>>(slots, ss, Wk, bk, Wq, ws);
  k_main<<<B / 512, 256, 0, stream>>>(
      item, ws, bq, ws, out_slot_weights, out_selected, B);
  k_final<<<1, 64, 0, stream>>>(item, slots, usage, Wv, bv, ws,
                                out_new_slots, out_new_usage, B);
  long n4 = (long)B * D / 4;
  k_bcast<<<2048, 256, 0, stream>>>(ws, (float4*)out_output, n4);
}

// Round 18
// 108.211 us; speedup vs baseline: 2.2881x; 1.0355x over previous
//
#include <hip/hip_runtime.h>
#include <math.h>

#define D 64
#define S 4

typedef short short8 __attribute__((ext_vector_type(8)));
typedef float f32x4 __attribute__((ext_vector_type(4)));

// ---------------- workspace layout (float offsets) ----------------
#define WS_KEYS 0      // keys[S][D]
#define WS_ST   256    // st_norm[S]
#define WS_SUMS 260    // uw_sums[S] (atomic, zeroed each launch)
#define WS_LW   264    // last_writer[S] (int, -1 init)
#define WS_OUT1 272    // out1[D] (16B aligned)
#define WS_WF   512    // W bf16 fragments: 3 levels x 8 planes x 512 ushort

#define TANH1(V_) fmaf(-2.f, __builtin_amdgcn_rcpf(__expf(2.f * (V_)) + 1.f), 1.f)

// exact 3-level truncation split: fp32 mantissa (24b) = 3 x 8b bf16 chunks
// a1+a2+a3 == a bitwise; ~8 VALU ops.
__global__ void k_prep(const float* __restrict__ slots,
                       const float* __restrict__ ss,
                       const float* __restrict__ Wk,
                       const float* __restrict__ bk,
                       const float* __restrict__ Wq,
                       float* __restrict__ ws) {
  int t = threadIdx.x;  // 256 threads
  __shared__ float sl[S][D];
  { int s = t >> 6, d = t & 63; sl[s][d] = slots[s * D + d]; }
  __syncthreads();
  // keys: one thread per (s,d) element
  {
    int s = t >> 6, d = t & 63;
    float acc = bk[d];
    for (int k = 0; k < D; ++k) acc = fmaf(sl[s][k], Wk[d * D + k], acc);
    ws[WS_KEYS + s * D + d] = tanhf(acc);
  }
  // W fragments (trunc split), 4096 elements striped over 256 threads
  {
    unsigned short* wf = (unsigned short*)(ws + WS_WF);
    for (int idx = t; idx < 4096; idx += 256) {
      int p = idx >> 9, rem = idx & 511, lane = rem >> 3, j = rem & 7;
      int h = p >> 2, nb = p & 3;
      int n = nb * 16 + (lane & 15);
      int k = h * 32 + (lane >> 4) * 8 + j;
      float v = Wq[n * D + k];
      unsigned u1 = __float_as_uint(v);
      float r1 = v - __uint_as_float(u1 & 0xFFFF0000u);
      unsigned u2 = __float_as_uint(r1);
      float r2 = r1 - __uint_as_float(u2 & 0xFFFF0000u);
      unsigned u3 = __float_as_uint(r2);
      wf[idx] = (unsigned short)(u1 >> 16);
      wf[4096 + idx] = (unsigned short)(u2 >> 16);
      wf[8192 + idx] = (unsigned short)(u3 >> 16);
    }
  }
  if (t < S) {
    ws[WS_SUMS + t] = 0.f;
    ((int*)ws)[WS_LW + t] = -1;
  }
  if (t == 0) {
    float st[S]; float tot = 0.f;
    for (int s = 0; s < S; ++s) {
      float x = ss[s];
      float sp = log1pf(expf(-fabsf(x))) + fmaxf(x, 0.f);  // softplus
      st[s] = sp; tot += sp;
    }
    for (int s = 0; s < S; ++s) ws[WS_ST + s] = st[s] / tot;
  }
}

#define SPLITJ(H_, J_, V_) { \
  float v_ = (V_); \
  unsigned u1_ = __float_as_uint(v_); \
  float r1_ = v_ - __uint_as_float(u1_ & 0xFFFF0000u); \
  unsigned u2_ = __float_as_uint(r1_); \
  float r2_ = r1_ - __uint_as_float(u2_ & 0xFFFF0000u); \
  unsigned u3_ = __float_as_uint(r2_); \
  a1[H_][J_] = (short)(u1_ >> 16); \
  a2[H_][J_] = (short)(u2_ >> 16); \
  a3[H_][J_] = (short)(u3_ >> 16); }

// MFMA kernel: W register-resident as lane-distributed bf16 fragments (3
// exact trunc-split levels). Per wave-iter: 16 rows, 48 MFMAs, epilogue sims
// via 16-lane shfl_xor tree. C/D layout (HW-verified m89): col=lane&15,
// row=(lane>>4)*4+reg. A/B share the (lane>>4,j)->k map so K-perm cancels.
__launch_bounds__(256)
__global__ void k_main(const float* __restrict__ item,
                       const float* __restrict__ ws,    // keys/st + wf
                       const float* __restrict__ bq,
                       float* red,                      // ws (atomics)
                       float* __restrict__ slot_weights,
                       float* __restrict__ selected,
                       int B) {
  __shared__ float red_sum[4][S];
  __shared__ int   red_lw[4][S];

  int t = threadIdx.x;
  int w = t >> 6, lane = t & 63;
  int lrow = lane & 15, g = lane >> 4;
  long base = (long)blockIdx.x * 512;

  // ---- persistent W fragments: 24 short8 = 96 VGPR ----
  const short8* wfv = (const short8*)(ws + WS_WF);
  short8 B1[2][4], B2[2][4], B3[2][4];
  #pragma unroll
  for (int h = 0; h < 2; ++h)
    #pragma unroll
    for (int nb = 0; nb < 4; ++nb) {
      B1[h][nb] = wfv[(h * 4 + nb) * 64 + lane];
      B2[h][nb] = wfv[512 + (h * 4 + nb) * 64 + lane];
      B3[h][nb] = wfv[1024 + (h * 4 + nb) * 64 + lane];
    }

  // per-lane keys fragment and bias
  float kf[4][4], bqv[4];
  #pragma unroll
  for (int nb = 0; nb < 4; ++nb) {
    bqv[nb] = bq[nb * 16 + lrow];
    #pragma unroll
    for (int s = 0; s < S; ++s) kf[s][nb] = ws[WS_KEYS + s * D + nb * 16 + lrow];
  }
  float s0 = ws[WS_ST + 0], s1 = ws[WS_ST + 1];
  float s2 = ws[WS_ST + 2], s3 = ws[WS_ST + 3];

  float usum[S] = {0.f, 0.f, 0.f, 0.f};
  int   lmax[S] = {-1, -1, -1, -1};

  #pragma unroll 1
  for (int it = 0; it < 8; ++it) {
    long r0 = base + it * 64 + (long)w * 16;
    const float4* xr = (const float4*)(item + (r0 + lrow) * D);
    float4 p0 = xr[g * 2 + 0], p1 = xr[g * 2 + 1];
    float4 p2 = xr[8 + g * 2 + 0], p3 = xr[8 + g * 2 + 1];

    short8 a1[2], a2[2], a3[2];
    SPLITJ(0, 0, p0.x) SPLITJ(0, 1, p0.y) SPLITJ(0, 2, p0.z) SPLITJ(0, 3, p0.w)
    SPLITJ(0, 4, p1.x) SPLITJ(0, 5, p1.y) SPLITJ(0, 6, p1.z) SPLITJ(0, 7, p1.w)
    SPLITJ(1, 0, p2.x) SPLITJ(1, 1, p2.y) SPLITJ(1, 2, p2.z) SPLITJ(1, 3, p2.w)
    SPLITJ(1, 4, p3.x) SPLITJ(1, 5, p3.y) SPLITJ(1, 6, p3.z) SPLITJ(1, 7, p3.w)

    f32x4 acc[4];
    #pragma unroll
    for (int nb = 0; nb < 4; ++nb) acc[nb] = (f32x4){0.f, 0.f, 0.f, 0.f};

    #pragma unroll
    for (int h = 0; h < 2; ++h) {
      #pragma unroll
      for (int nb = 0; nb < 4; ++nb) {
        acc[nb] = __builtin_amdgcn_mfma_f32_16x16x32_bf16(a1[h], B1[h][nb], acc[nb], 0, 0, 0);
        acc[nb] = __builtin_amdgcn_mfma_f32_16x16x32_bf16(a1[h], B2[h][nb], acc[nb], 0, 0, 0);
        acc[nb] = __builtin_amdgcn_mfma_f32_16x16x32_bf16(a2[h], B1[h][nb], acc[nb], 0, 0, 0);
        acc[nb] = __builtin_amdgcn_mfma_f32_16x16x32_bf16(a1[h], B3[h][nb], acc[nb], 0, 0, 0);
        acc[nb] = __builtin_amdgcn_mfma_f32_16x16x32_bf16(a3[h], B1[h][nb], acc[nb], 0, 0, 0);
        acc[nb] = __builtin_amdgcn_mfma_f32_16x16x32_bf16(a2[h], B2[h][nb], acc[nb], 0, 0, 0);
      }
    }

    // epilogue: tanh + partial sims over this lane's 4 rows x 4 slots
    float ps[4][4];
    #pragma unroll
    for (int r_ = 0; r_ < 4; ++r_)
      #pragma unroll
      for (int s = 0; s < S; ++s) ps[r_][s] = 0.f;
    #pragma unroll
    for (int nb = 0; nb < 4; ++nb)
      #pragma unroll
      for (int r_ = 0; r_ < 4; ++r_) {
        float q = TANH1(acc[nb][r_] + bqv[nb]);
        #pragma unroll
        for (int s = 0; s < S; ++s) ps[r_][s] = fmaf(q, kf[s][nb], ps[r_][s]);
      }
    #pragma unroll
    for (int m_ = 1; m_ <= 8; m_ <<= 1)
      #pragma unroll
      for (int r_ = 0; r_ < 4; ++r_)
        #pragma unroll
        for (int s = 0; s < S; ++s) ps[r_][s] += __shfl_xor(ps[r_][s], m_);

    // owner lanes (lrow<4) finish row m = g*4 + lrow
    bool act = lrow < 4;
    float q0 = ps[0][0], q1 = ps[0][1], q2 = ps[0][2], q3 = ps[0][3];
    if (lrow == 1)      { q0 = ps[1][0]; q1 = ps[1][1]; q2 = ps[1][2]; q3 = ps[1][3]; }
    else if (lrow == 2) { q0 = ps[2][0]; q1 = ps[2][1]; q2 = ps[2][2]; q3 = ps[2][3]; }
    else if (lrow == 3) { q0 = ps[3][0]; q1 = ps[3][1]; q2 = ps[3][2]; q3 = ps[3][3]; }
    long grow = r0 + g * 4 + lrow;

    if (act) {
      float m = fmaxf(fmaxf(q0, q1), fmaxf(q2, q3));
      float e0 = expf(q0 - m), e1 = expf(q1 - m), e2 = expf(q2 - m), e3 = expf(q3 - m);
      float se = e0 + e1 + e2 + e3;
      float w0 = e0 / se, w1 = e1 / se, w2 = e2 / se, w3 = e3 / se;
      *(float4*)(slot_weights + grow * S) = make_float4(w0, w1, w2, w3);
      float u0 = w0 * s0, u1 = w1 * s1, u2 = w2 * s2, u3 = w3 * s3;
      float us = u0 + u1 + u2 + u3;
      u0 /= us; u1 /= us; u2 /= us; u3 /= us;
      int sel = 0; float best = u0;
      if (u1 > best) { best = u1; sel = 1; }
      if (u2 > best) { best = u2; sel = 2; }
      if (u3 > best) { best = u3; sel = 3; }
      selected[grow] = (float)sel;
      usum[0] += u0; usum[1] += u1; usum[2] += u2; usum[3] += u3;
      #pragma unroll
      for (int s = 0; s < S; ++s)
        if (sel == s && (int)grow > lmax[s]) lmax[s] = (int)grow;
    }
  }

  // ---- block reduction: uw sums (add) and last-writer (max) ----
  #pragma unroll
  for (int off = 32; off > 0; off >>= 1) {
    #pragma unroll
    for (int s = 0; s < S; ++s) {
      usum[s] += __shfl_down(usum[s], off);
      int m = __shfl_down(lmax[s], off);
      lmax[s] = lmax[s] > m ? lmax[s] : m;
    }
  }
  if (lane == 0) {
    #pragma unroll
    for (int s = 0; s < S; ++s) { red_sum[w][s] = usum[s]; red_lw[w][s] = lmax[s]; }
  }
  __syncthreads();
  if (t < S) {
    float tot = red_sum[0][t] + red_sum[1][t] + red_sum[2][t] + red_sum[3][t];
    atomicAdd(&red[WS_SUMS + t], tot);
    int lm = red_lw[0][t];
    if (red_lw[1][t] > lm) lm = red_lw[1][t];
    if (red_lw[2][t] > lm) lm = red_lw[2][t];
    if (red_lw[3][t] > lm) lm = red_lw[3][t];
    atomicMax((int*)red + WS_LW + t, lm);
  }
}

__global__ void k_final(const float* __restrict__ item,
                        const float* __restrict__ slots,
                        const float* __restrict__ usage,
                        const float* __restrict__ Wv,
                        const float* __restrict__ bv,
                        float* ws,
                        float* __restrict__ out_ns,
                        float* __restrict__ out_nu,
                        int B) {
  int t = threadIdx.x;  // 256 threads
  int w = t >> 6, d = t & 63;
  __shared__ float mean[D];
  __shared__ float part[4][D];
  const int* lw = (const int*)ws + WS_LW;
  if (w == 0) {
    float nsv[S];
    for (int s = 0; s < S; ++s) {
      int wr = lw[s];
      float v = (wr >= 0) ? item[(size_t)wr * D + d] : slots[s * D + d];
      nsv[s] = v;
      out_ns[s * D + d] = v;
    }
    mean[d] = (nsv[0] + nsv[1] + nsv[2] + nsv[3]) * 0.25f;
  }
  __syncthreads();
  float acc = 0.f;
  for (int k = w * 16; k < w * 16 + 16; ++k) acc = fmaf(mean[k], Wv[d * D + k], acc);
  part[w][d] = acc;
  __syncthreads();
  if (w == 0) {
    float a = part[0][d] + part[1][d] + part[2][d] + part[3][d] + bv[d];
    ws[WS_OUT1 + d] = tanhf(a);
    if (d < S) out_nu[d] = usage[d] * 0.9f + ws[WS_SUMS + d] / (float)B;
  }
}

__global__ void k_bcast(const float* __restrict__ ws,
                        float4* __restrict__ out, long n4) {
  __shared__ float4 o4[16];
  if (threadIdx.x < 16) o4[threadIdx.x] = ((const float4*)(ws + WS_OUT1))[threadIdx.x];
  __syncthreads();
  long i = (long)blockIdx.x * blockDim.x + threadIdx.x;
  long stride = (long)gridDim.x * blockDim.x;
  for (; i < n4; i += stride) out[i] = o4[i & 15];
}

extern "C" void kernel_launch(void* const* d_in, const int* in_sizes, int n_in,
                              void* d_out, int out_size, void* d_ws, size_t ws_size,
                              hipStream_t stream) {
  const float* item  = (const float*)d_in[0];
  const float* slots = (const float*)d_in[1];
  const float* ss    = (const float*)d_in[2];
  const float* usage = (const float*)d_in[3];
  const float* Wq    = (const float*)d_in[4];
  const float* bq    = (const float*)d_in[5];
  const float* Wk    = (const float*)d_in[6];
  const float* bk    = (const float*)d_in[7];
  const float* Wv    = (const float*)d_in[8];
  const float* bv    = (const float*)d_in[9];
  int B = in_sizes[0] / D;
  float* ws = (float*)d_ws;

  float* out_output       = (float*)d_out;
  float* out_new_slots    = out_output + (size_t)B * D;
  float* out_new_usage    = out_new_slots + S * D;
  float* out_selected     = out_new_usage + S;
  float* out_slot_weights = out_selected + B;

  k_prep<<<1, 256, 0, stream>>>(slots, ss, Wk, bk, Wq, ws);
  k_main<<<B / 512, 256, 0, stream>>>(
      item, ws, bq, ws, out_slot_weights, out_selected, B);
  k_final<<<1, 256, 0, stream>>>(item, slots, usage, Wv, bv, ws,
                                 out_new_slots, out_new_usage, B);
  long n4 = (long)B * D / 4;
  k_bcast<<<2048, 256, 0, stream>>>(ws, (float4*)out_output, n4);
}

// Round 19
// 104.650 us; speedup vs baseline: 2.3660x; 1.0340x over previous
//
#include <hip/hip_runtime.h>
#include <math.h>

#define D 64
#define S 4

typedef short short8 __attribute__((ext_vector_type(8)));
typedef float f32x4 __attribute__((ext_vector_type(4)));

// ---------------- workspace layout (float offsets) ----------------
#define WS_KEYS 0      // keys[S][D]
#define WS_ST   256    // st_norm[S]
#define WS_SUMS 260    // uw_sums[S] (atomic, zeroed each launch)
#define WS_LW   264    // last_writer[S] (int, -1 init)
#define WS_OUT1 272    // out1[D] (16B aligned)
#define WS_WF   512    // W bf16 fragments: 3 levels x 8 planes x 512 ushort

#define TANH1(V_) fmaf(-2.f, __builtin_amdgcn_rcpf(__expf(2.f * (V_)) + 1.f), 1.f)

// exact 3-level truncation split: fp32 mantissa (24b) = 3 x 8b bf16 chunks
__global__ void k_prep(const float* __restrict__ slots,
                       const float* __restrict__ ss,
                       const float* __restrict__ Wk,
                       const float* __restrict__ bk,
                       const float* __restrict__ Wq,
                       float* __restrict__ ws) {
  int t = threadIdx.x;  // 256 threads
  __shared__ float sl[S][D];
  { int s = t >> 6, d = t & 63; sl[s][d] = slots[s * D + d]; }
  __syncthreads();
  {
    int s = t >> 6, d = t & 63;
    float acc = bk[d];
    for (int k = 0; k < D; ++k) acc = fmaf(sl[s][k], Wk[d * D + k], acc);
    ws[WS_KEYS + s * D + d] = tanhf(acc);
  }
  {
    unsigned short* wf = (unsigned short*)(ws + WS_WF);
    for (int idx = t; idx < 4096; idx += 256) {
      int p = idx >> 9, rem = idx & 511, lane = rem >> 3, j = rem & 7;
      int h = p >> 2, nb = p & 3;
      int n = nb * 16 + (lane & 15);
      int k = h * 32 + (lane >> 4) * 8 + j;
      float v = Wq[n * D + k];
      unsigned u1 = __float_as_uint(v);
      float r1 = v - __uint_as_float(u1 & 0xFFFF0000u);
      unsigned u2 = __float_as_uint(r1);
      float r2 = r1 - __uint_as_float(u2 & 0xFFFF0000u);
      unsigned u3 = __float_as_uint(r2);
      wf[idx] = (unsigned short)(u1 >> 16);
      wf[4096 + idx] = (unsigned short)(u2 >> 16);
      wf[8192 + idx] = (unsigned short)(u3 >> 16);
    }
  }
  if (t < S) {
    ws[WS_SUMS + t] = 0.f;
    ((int*)ws)[WS_LW + t] = -1;
  }
  if (t == 0) {
    float st[S]; float tot = 0.f;
    for (int s = 0; s < S; ++s) {
      float x = ss[s];
      float sp = log1pf(expf(-fabsf(x))) + fmaxf(x, 0.f);  // softplus
      st[s] = sp; tot += sp;
    }
    for (int s = 0; s < S; ++s) ws[WS_ST + s] = st[s] / tot;
  }
}

#define SPLITJ(H_, J_, V_) { \
  float v_ = (V_); \
  unsigned u1_ = __float_as_uint(v_); \
  float r1_ = v_ - __uint_as_float(u1_ & 0xFFFF0000u); \
  unsigned u2_ = __float_as_uint(r1_); \
  float r2_ = r1_ - __uint_as_float(u2_ & 0xFFFF0000u); \
  unsigned u3_ = __float_as_uint(r2_); \
  a1[H_][J_] = (short)(u1_ >> 16); \
  a2[H_][J_] = (short)(u2_ >> 16); \
  a3[H_][J_] = (short)(u3_ >> 16); }

// MFMA kernel with one-deep x prefetch: iter N's loads issue before iter N-1's
// split/MFMA/epilogue, hiding global latency under compute. W register-
// resident (3 trunc-split levels, 24 short8). C/D layout (m89): col=lane&15,
// row=(lane>>4)*4+reg. A/B share (lane>>4,j)->k map so K-perm cancels.
__launch_bounds__(256)
__global__ void k_main(const float* __restrict__ item,
                       const float* __restrict__ ws,    // keys/st + wf
                       const float* __restrict__ bq,
                       float* red,                      // ws (atomics)
                       float* __restrict__ slot_weights,
                       float* __restrict__ selected,
                       int B) {
  __shared__ float red_sum[4][S];
  __shared__ int   red_lw[4][S];

  int t = threadIdx.x;
  int w = t >> 6, lane = t & 63;
  int lrow = lane & 15, g = lane >> 4;
  long base = (long)blockIdx.x * 512;

  // ---- persistent W fragments: 24 short8 = 96 VGPR ----
  const short8* wfv = (const short8*)(ws + WS_WF);
  short8 B1[2][4], B2[2][4], B3[2][4];
  #pragma unroll
  for (int h = 0; h < 2; ++h)
    #pragma unroll
    for (int nb = 0; nb < 4; ++nb) {
      B1[h][nb] = wfv[(h * 4 + nb) * 64 + lane];
      B2[h][nb] = wfv[512 + (h * 4 + nb) * 64 + lane];
      B3[h][nb] = wfv[1024 + (h * 4 + nb) * 64 + lane];
    }

  float kf[4][4], bqv[4];
  #pragma unroll
  for (int nb = 0; nb < 4; ++nb) {
    bqv[nb] = bq[nb * 16 + lrow];
    #pragma unroll
    for (int s = 0; s < S; ++s) kf[s][nb] = ws[WS_KEYS + s * D + nb * 16 + lrow];
  }
  float s0 = ws[WS_ST + 0], s1 = ws[WS_ST + 1];
  float s2 = ws[WS_ST + 2], s3 = ws[WS_ST + 3];

  float usum[S] = {0.f, 0.f, 0.f, 0.f};
  int   lmax[S] = {-1, -1, -1, -1};

  // ---- prefetch iter 0 ----
  const float4* xr = (const float4*)(item + (base + (long)w * 16 + lrow) * D);
  float4 p0 = xr[g * 2 + 0], p1 = xr[g * 2 + 1];
  float4 p2 = xr[8 + g * 2 + 0], p3 = xr[8 + g * 2 + 1];

  #pragma unroll 1
  for (int it = 0; it < 8; ++it) {
    long r0 = base + it * 64 + (long)w * 16;
    float4 c0 = p0, c1 = p1, c2 = p2, c3 = p3;
    if (it < 7) {                       // uniform-trip prefetch of iter+1
      const float4* xn = (const float4*)(item + (r0 + 64 + lrow) * D);
      p0 = xn[g * 2 + 0]; p1 = xn[g * 2 + 1];
      p2 = xn[8 + g * 2 + 0]; p3 = xn[8 + g * 2 + 1];
    }

    short8 a1[2], a2[2], a3[2];
    SPLITJ(0, 0, c0.x) SPLITJ(0, 1, c0.y) SPLITJ(0, 2, c0.z) SPLITJ(0, 3, c0.w)
    SPLITJ(0, 4, c1.x) SPLITJ(0, 5, c1.y) SPLITJ(0, 6, c1.z) SPLITJ(0, 7, c1.w)
    SPLITJ(1, 0, c2.x) SPLITJ(1, 1, c2.y) SPLITJ(1, 2, c2.z) SPLITJ(1, 3, c2.w)
    SPLITJ(1, 4, c3.x) SPLITJ(1, 5, c3.y) SPLITJ(1, 6, c3.z) SPLITJ(1, 7, c3.w)

    f32x4 acc[4];
    #pragma unroll
    for (int nb = 0; nb < 4; ++nb) acc[nb] = (f32x4){0.f, 0.f, 0.f, 0.f};

    #pragma unroll
    for (int h = 0; h < 2; ++h) {
      #pragma unroll
      for (int nb = 0; nb < 4; ++nb) {
        acc[nb] = __builtin_amdgcn_mfma_f32_16x16x32_bf16(a1[h], B1[h][nb], acc[nb], 0, 0, 0);
        acc[nb] = __builtin_amdgcn_mfma_f32_16x16x32_bf16(a1[h], B2[h][nb], acc[nb], 0, 0, 0);
        acc[nb] = __builtin_amdgcn_mfma_f32_16x16x32_bf16(a2[h], B1[h][nb], acc[nb], 0, 0, 0);
        acc[nb] = __builtin_amdgcn_mfma_f32_16x16x32_bf16(a1[h], B3[h][nb], acc[nb], 0, 0, 0);
        acc[nb] = __builtin_amdgcn_mfma_f32_16x16x32_bf16(a3[h], B1[h][nb], acc[nb], 0, 0, 0);
        acc[nb] = __builtin_amdgcn_mfma_f32_16x16x32_bf16(a2[h], B2[h][nb], acc[nb], 0, 0, 0);
      }
    }

    // epilogue: tanh + partial sims over this lane's 4 rows x 4 slots
    float ps[4][4];
    #pragma unroll
    for (int r_ = 0; r_ < 4; ++r_)
      #pragma unroll
      for (int s = 0; s < S; ++s) ps[r_][s] = 0.f;
    #pragma unroll
    for (int nb = 0; nb < 4; ++nb)
      #pragma unroll
      for (int r_ = 0; r_ < 4; ++r_) {
        float q = TANH1(acc[nb][r_] + bqv[nb]);
        #pragma unroll
        for (int s = 0; s < S; ++s) ps[r_][s] = fmaf(q, kf[s][nb], ps[r_][s]);
      }
    #pragma unroll
    for (int m_ = 1; m_ <= 8; m_ <<= 1)
      #pragma unroll
      for (int r_ = 0; r_ < 4; ++r_)
        #pragma unroll
        for (int s = 0; s < S; ++s) ps[r_][s] += __shfl_xor(ps[r_][s], m_);

    bool act = lrow < 4;
    float q0 = ps[0][0], q1 = ps[0][1], q2 = ps[0][2], q3 = ps[0][3];
    if (lrow == 1)      { q0 = ps[1][0]; q1 = ps[1][1]; q2 = ps[1][2]; q3 = ps[1][3]; }
    else if (lrow == 2) { q0 = ps[2][0]; q1 = ps[2][1]; q2 = ps[2][2]; q3 = ps[2][3]; }
    else if (lrow == 3) { q0 = ps[3][0]; q1 = ps[3][1]; q2 = ps[3][2]; q3 = ps[3][3]; }
    long grow = r0 + g * 4 + lrow;

    if (act) {
      float m = fmaxf(fmaxf(q0, q1), fmaxf(q2, q3));
      float e0 = expf(q0 - m), e1 = expf(q1 - m), e2 = expf(q2 - m), e3 = expf(q3 - m);
      float se = e0 + e1 + e2 + e3;
      float w0 = e0 / se, w1 = e1 / se, w2 = e2 / se, w3 = e3 / se;
      *(float4*)(slot_weights + grow * S) = make_float4(w0, w1, w2, w3);
      float u0 = w0 * s0, u1 = w1 * s1, u2 = w2 * s2, u3 = w3 * s3;
      float us = u0 + u1 + u2 + u3;
      u0 /= us; u1 /= us; u2 /= us; u3 /= us;
      int sel = 0; float best = u0;
      if (u1 > best) { best = u1; sel = 1; }
      if (u2 > best) { best = u2; sel = 2; }
      if (u3 > best) { best = u3; sel = 3; }
      selected[grow] = (float)sel;
      usum[0] += u0; usum[1] += u1; usum[2] += u2; usum[3] += u3;
      #pragma unroll
      for (int s = 0; s < S; ++s)
        if (sel == s && (int)grow > lmax[s]) lmax[s] = (int)grow;
    }
  }

  // ---- block reduction: uw sums (add) and last-writer (max) ----
  #pragma unroll
  for (int off = 32; off > 0; off >>= 1) {
    #pragma unroll
    for (int s = 0; s < S; ++s) {
      usum[s] += __shfl_down(usum[s], off);
      int m = __shfl_down(lmax[s], off);
      lmax[s] = lmax[s] > m ? lmax[s] : m;
    }
  }
  if (lane == 0) {
    #pragma unroll
    for (int s = 0; s < S; ++s) { red_sum[w][s] = usum[s]; red_lw[w][s] = lmax[s]; }
  }
  __syncthreads();
  if (t < S) {
    float tot = red_sum[0][t] + red_sum[1][t] + red_sum[2][t] + red_sum[3][t];
    atomicAdd(&red[WS_SUMS + t], tot);
    int lm = red_lw[0][t];
    if (red_lw[1][t] > lm) lm = red_lw[1][t];
    if (red_lw[2][t] > lm) lm = red_lw[2][t];
    if (red_lw[3][t] > lm) lm = red_lw[3][t];
    atomicMax((int*)red + WS_LW + t, lm);
  }
}

__global__ void k_final(const float* __restrict__ item,
                        const float* __restrict__ slots,
                        const float* __restrict__ usage,
                        const float* __restrict__ Wv,
                        const float* __restrict__ bv,
                        float* ws,
                        float* __restrict__ out_ns,
                        float* __restrict__ out_nu,
                        int B) {
  int t = threadIdx.x;  // 256 threads
  int w = t >> 6, d = t & 63;
  __shared__ float mean[D];
  __shared__ float part[4][D];
  const int* lw = (const int*)ws + WS_LW;
  if (w == 0) {
    float nsv[S];
    for (int s = 0; s < S; ++s) {
      int wr = lw[s];
      float v = (wr >= 0) ? item[(size_t)wr * D + d] : slots[s * D + d];
      nsv[s] = v;
      out_ns[s * D + d] = v;
    }
    mean[d] = (nsv[0] + nsv[1] + nsv[2] + nsv[3]) * 0.25f;
  }
  __syncthreads();
  float acc = 0.f;
  for (int k = w * 16; k < w * 16 + 16; ++k) acc = fmaf(mean[k], Wv[d * D + k], acc);
  part[w][d] = acc;
  __syncthreads();
  if (w == 0) {
    float a = part[0][d] + part[1][d] + part[2][d] + part[3][d] + bv[d];
    ws[WS_OUT1 + d] = tanhf(a);
    if (d < S) out_nu[d] = usage[d] * 0.9f + ws[WS_SUMS + d] / (float)B;
  }
}

__global__ void k_bcast(const float* __restrict__ ws,
                        float4* __restrict__ out, long n4) {
  __shared__ float4 o4[16];
  if (threadIdx.x < 16) o4[threadIdx.x] = ((const float4*)(ws + WS_OUT1))[threadIdx.x];
  __syncthreads();
  long i = (long)blockIdx.x * blockDim.x + threadIdx.x;
  long stride = (long)gridDim.x * blockDim.x;
  for (; i < n4; i += stride) out[i] = o4[i & 15];
}

extern "C" void kernel_launch(void* const* d_in, const int* in_sizes, int n_in,
                              void* d_out, int out_size, void* d_ws, size_t ws_size,
                              hipStream_t stream) {
  const float* item  = (const float*)d_in[0];
  const float* slots = (const float*)d_in[1];
  const float* ss    = (const float*)d_in[2];
  const float* usage = (const float*)d_in[3];
  const float* Wq    = (const float*)d_in[4];
  const float* bq    = (const float*)d_in[5];
  const float* Wk    = (const float*)d_in[6];
  const float* bk    = (const float*)d_in[7];
  const float* Wv    = (const float*)d_in[8];
  const float* bv    = (const float*)d_in[9];
  int B = in_sizes[0] / D;
  float* ws = (float*)d_ws;

  float* out_output       = (float*)d_out;
  float* out_new_slots    = out_output + (size_t)B * D;
  float* out_new_usage    = out_new_slots + S * D;
  float* out_selected     = out_new_usage + S;
  float* out_slot_weights = out_selected + B;

  k_prep<<<1, 256, 0, stream>>>(slots, ss, Wk, bk, Wq, ws);
  k_main<<<B / 512, 256, 0, stream>>>(
      item, ws, bq, ws, out_slot_weights, out_selected, B);
  k_final<<<1, 256, 0, stream>>>(item, slots, usage, Wv, bv, ws,
                                 out_new_slots, out_new_usage, B);
  long n4 = (long)B * D / 4;
  k_bcast<<<2048, 256, 0, stream>>>(ws, (float4*)out_output, n4);
}